// Round 8
// baseline (860.597 us; speedup 1.0000x reference)
//
#include <hip/hip_runtime.h>

#define BB 32
#define NN 576
#define DD 1024
#define KK 128
#define HS_N 577

// ---------------- norm kernel: inv[b,n] = 1/||feats[b,n,:]|| ----------------
__global__ __launch_bounds__(256) void norm_kernel(const float* __restrict__ hs,
                                                   float* __restrict__ inv) {
    int row = blockIdx.x;              // b*NN + n
    int b = row / NN, n = row % NN;
    const float4* p = (const float4*)(hs + ((size_t)b * HS_N + n + 1) * DD);
    int t = threadIdx.x;
    float4 v = p[t];
    double s = (double)v.x * v.x + (double)v.y * v.y + (double)v.z * v.z + (double)v.w * v.w;
    for (int off = 32; off; off >>= 1) s += __shfl_xor(s, off);
    __shared__ double wsum[4];
    int lane = t & 63, w = t >> 6;
    if (lane == 0) wsum[w] = s;
    __syncthreads();
    if (t == 0) {
        double tot = wsum[0] + wsum[1] + wsum[2] + wsum[3];
        inv[row] = 1.0f / (float)sqrt(tot);
    }
}

// ---------------- sim GEMM (symmetric): only 45 upper-tri 64x64 tile pairs --
#define KC 16
#define LDT 68   // padded LDS stride
#define TLD 68   // transpose-bounce stride
__global__ __launch_bounds__(256) void sim_kernel(const float* __restrict__ hs,
                                                  const float* __restrict__ inv,
                                                  float* __restrict__ sim) {
    int b = blockIdx.z;
    int l = blockIdx.x;                // 0..44 -> (ti,tj), ti<=tj
    int ti = 0;
    while (l >= 9 - ti) { l -= 9 - ti; ti++; }
    int tj = ti + l;
    int m0 = ti * 64, n0 = tj * 64;
    const float* feats = hs + ((size_t)b * HS_N + 1) * DD;
    __shared__ float As[KC * LDT];
    __shared__ float Bs[KC * LDT];
    __shared__ float tile[64 * TLD];
    int t = threadIdx.x;
    int lrow = t >> 2, lc4 = (t & 3) << 2;     // 64 rows x 4 float4-cols
    float invA = inv[b * NN + m0 + lrow];
    float invB = inv[b * NN + n0 + lrow];
    const float* gA = feats + (size_t)(m0 + lrow) * DD + lc4;
    const float* gB = feats + (size_t)(n0 + lrow) * DD + lc4;
    int tx = t & 15, ty = t >> 4;
    float acc[4][4] = {};
    for (int k0 = 0; k0 < DD; k0 += KC) {
        float4 a = *(const float4*)(gA + k0);
        float4 bv = *(const float4*)(gB + k0);
        __syncthreads();
        // store transposed [k][m], scaled at load (matches reference normalize-then-dot)
        As[(lc4 + 0) * LDT + lrow] = a.x * invA;
        As[(lc4 + 1) * LDT + lrow] = a.y * invA;
        As[(lc4 + 2) * LDT + lrow] = a.z * invA;
        As[(lc4 + 3) * LDT + lrow] = a.w * invA;
        Bs[(lc4 + 0) * LDT + lrow] = bv.x * invB;
        Bs[(lc4 + 1) * LDT + lrow] = bv.y * invB;
        Bs[(lc4 + 2) * LDT + lrow] = bv.z * invB;
        Bs[(lc4 + 3) * LDT + lrow] = bv.w * invB;
        __syncthreads();
#pragma unroll
        for (int kk = 0; kk < KC; kk++) {
            float4 av = *(const float4*)&As[kk * LDT + (tx << 2)];
            float4 bw = *(const float4*)&Bs[kk * LDT + (ty << 2)];
            float aa[4] = {av.x, av.y, av.z, av.w};
            float bb[4] = {bw.x, bw.y, bw.z, bw.w};
#pragma unroll
            for (int i = 0; i < 4; i++)
#pragma unroll
                for (int j = 0; j < 4; j++) acc[i][j] += aa[i] * bb[j];
        }
    }
    // normal-orientation tile write (coalesced float4)
#pragma unroll
    for (int i = 0; i < 4; i++) {
        size_t m = m0 + (tx << 2) + i;
        float4 o = {acc[i][0], acc[i][1], acc[i][2], acc[i][3]};
        *(float4*)(sim + ((size_t)b * NN + m) * NN + n0 + (ty << 2)) = o;
    }
    if (ti != tj) {
        // mirror tile via LDS bounce; same float values -> bitwise symmetric
        __syncthreads();
#pragma unroll
        for (int i = 0; i < 4; i++) {
            float4 o = {acc[i][0], acc[i][1], acc[i][2], acc[i][3]};
            *(float4*)&tile[((tx << 2) + i) * TLD + (ty << 2)] = o;
        }
        __syncthreads();
#pragma unroll
        for (int r = 0; r < 4; r++) {
            int a = (tx << 2) + r;                 // local n index (output row)
            float4 o;
            o.x = tile[((ty << 2) + 0) * TLD + a];
            o.y = tile[((ty << 2) + 1) * TLD + a];
            o.z = tile[((ty << 2) + 2) * TLD + a];
            o.w = tile[((ty << 2) + 3) * TLD + a];
            *(float4*)(sim + ((size_t)b * NN + n0 + a) * NN + m0 + (ty << 2)) = o;
        }
    }
}

// -------- init gains on all CUs: g0[b,m] = sum_n max(sim[b,m,n],0) ----------
__global__ __launch_bounds__(256) void init_gain_kernel(const float* __restrict__ sim,
                                                        double* __restrict__ g0) {
    int b = blockIdx.y;
    int m = (blockIdx.x << 2) + (threadIdx.x >> 6);
    int lane = threadIdx.x & 63;
    const float* row = sim + ((size_t)b * NN + m) * NN;
    double s = 0.0;
#pragma unroll
    for (int j = 0; j < 9; j++) s += (double)fmaxf(row[(j << 6) + lane], 0.f);
    for (int off = 32; off; off >>= 1) s += __shfl_xor(s, off);
    if (lane == 0) g0[b * NN + m] = s;
}

#define LD16(u) \
    int n##u = chlist[(j + u < cc) ? (j + u) : (cc - 1)];
#define XL16(u) \
    float x##u = col[(size_t)n##u * NN];
#define ON16(u) \
    float2 on##u = ovnw[n##u];
#define AC16(u) \
    { double d = (double)fmaxf(x##u - on##u.y, 0.f) - (double)fmaxf(x##u - on##u.x, 0.f); \
      g += (j + u < cc) ? d : 0.0; }

// ------- selection: 9 waves x 1 candidate, 2 barriers/step, named-scalar ILP
// Thread t owns candidate t; gain g (fp64) + cmax[t] in registers. Per step:
//   phase1 (k>0): rebuild ascending chlist from 9 ballot masks (each wave
//     writes its own full copy; same-value cross-wave races benign), then
//     delta-update g in rounds of 16 NAMED scalar loads (no arrays -> no
//     register-pressure collapse; no guards between loads -> no execz
//     serialization; clamped index + post-masked contribution).
//   argmax: wave shuffle (fp64, smallest-index ties) -> rv/ri -> barrier A
//     -> all threads scan 9 slots (broadcast LDS reads).
//   tail: coalesced row-mstar load, register cmax update, ballot -> chmask[w],
//     (old,new) float2 -> LDS, selseq in LDS, barrier B. No global ops in loop.
__global__ __launch_bounds__(576) void select_kernel(const float* __restrict__ sim,
                                                     const double* __restrict__ g0,
                                                     const float* __restrict__ cls,
                                                     float* __restrict__ out_idx,
                                                     int* __restrict__ gsorted) {
    int b = blockIdx.x;
    const float* S = sim + (size_t)b * NN * NN;
    int t = threadIdx.x, lane = t & 63, w = t >> 6;
    __shared__ float2 ovnw[NN];            // (old cmax, new cmax) per column
    __shared__ int    chlist[NN];
    __shared__ unsigned long long chmask[9];
    __shared__ double rv[9];
    __shared__ int    ri[9];
    __shared__ float  selseq[KK];
    __shared__ int    wcnt[9];

    double clsv = (double)cls[b * NN + t];
    double g = g0[b * NN + t];
    bool sel = false;
    float mycmax = 0.f;
    const float* col = S + t;              // column t: col[n*NN]

    for (int k = 0; k < KK; k++) {
        // ---- phase 1: delta-update over step-(k-1) changed columns ----
        if (k > 0) {
            int pos = 0;
#pragma unroll
            for (int q = 0; q < 9; q++) {
                unsigned long long m = chmask[q];
                if ((m >> lane) & 1ull)
                    chlist[pos + __popcll(m & ((1ull << lane) - 1ull))] = (q << 6) + lane;
                pos += __popcll(m);
            }
            int cc = pos;
            for (int j = 0; j < cc; j += 16) {
                LD16(0) LD16(1) LD16(2) LD16(3) LD16(4) LD16(5) LD16(6) LD16(7)
                LD16(8) LD16(9) LD16(10) LD16(11) LD16(12) LD16(13) LD16(14) LD16(15)
                XL16(0) XL16(1) XL16(2) XL16(3) XL16(4) XL16(5) XL16(6) XL16(7)
                XL16(8) XL16(9) XL16(10) XL16(11) XL16(12) XL16(13) XL16(14) XL16(15)
                ON16(0) ON16(1) ON16(2) ON16(3) ON16(4) ON16(5) ON16(6) ON16(7)
                ON16(8) ON16(9) ON16(10) ON16(11) ON16(12) ON16(13) ON16(14) ON16(15)
                AC16(0) AC16(1) AC16(2) AC16(3) AC16(4) AC16(5) AC16(6) AC16(7)
                AC16(8) AC16(9) AC16(10) AC16(11) AC16(12) AC16(13) AC16(14) AC16(15)
            }
        }
        // ---- wave argmax (smallest-index tie-break = jnp.argmax) ----
        double v = sel ? -1.0 : g * clsv;      // gains >= 0 for unselected
        int idx = t;
        for (int off = 32; off; off >>= 1) {
            double ov = __shfl_xor(v, off);
            int oi = __shfl_xor(idx, off);
            if (ov > v || (ov == v && oi < idx)) { v = ov; idx = oi; }
        }
        if (lane == 0) { rv[w] = v; ri[w] = idx; }
        __syncthreads();                           // A
        double bv = rv[0]; int mstar = ri[0];
#pragma unroll
        for (int q = 1; q < 9; q++) {
            double qv = rv[q]; int qi = ri[q];
            if (qv > bv || (qv == bv && qi < mstar)) { bv = qv; mstar = qi; }
        }
        // ---- tail: coalesced row load, cmax update, ballot mask ----
        float srow = S[(size_t)mstar * NN + t];
        float old = mycmax;
        float nw = fmaxf(old, srow);
        bool ch = nw > old;
        unsigned long long m = __ballot(ch);
        ovnw[t] = make_float2(old, nw);
        mycmax = nw;
        if (lane == 0) chmask[w] = m;
        if (t == mstar) { sel = true; selseq[k] = (float)(mstar + 1); }
        __syncthreads();                           // B
    }

    // ---- epilogue: write selection order + sorted gather list ----
    if (t < KK) out_idx[b * KK + t] = selseq[t];
    unsigned long long mask = __ballot(sel);
    int rank = __popcll(mask & ((1ull << lane) - 1));
    if (lane == 0) wcnt[w] = __popcll(mask);
    __syncthreads();
    int pre = 0;
#pragma unroll
    for (int q = 0; q < 9; q++) if (q < w) pre += wcnt[q];
    if (sel) gsorted[b * KK + pre + rank] = t + 1;
}

// ---------------- gather: dominant_tokens[b,j,:] = hs[b, gsorted, :] --------
__global__ __launch_bounds__(256) void gather_kernel(const float* __restrict__ hs,
                                                     const int* __restrict__ gsorted,
                                                     float* __restrict__ out) {
    int blk = blockIdx.x;
    int b = blk >> 7, j = blk & 127;
    int row = gsorted[b * KK + j];
    const float4* src = (const float4*)(hs + ((size_t)b * HS_N + row) * DD);
    float4* dst = (float4*)(out + ((size_t)b * KK + j) * DD);
    dst[threadIdx.x] = src[threadIdx.x];
}

extern "C" void kernel_launch(void* const* d_in, const int* in_sizes, int n_in,
                              void* d_out, int out_size, void* d_ws, size_t ws_size,
                              hipStream_t stream) {
    const float* hs = (const float*)d_in[0];
    const float* cls = (const float*)d_in[1];
    // workspace layout: sim (42.5MB) | X: inv (norm->sim) / g0 (init->select,
    // lifetimes disjoint, g0 overlays inv) | gsorted (16KB)
    float* sim = (float*)d_ws;
    char* xregion = (char*)(sim + (size_t)BB * NN * NN);
    float* inv = (float*)xregion;                  // BB*NN floats
    double* g0 = (double*)xregion;                 // BB*NN doubles (overlay)
    int* gsorted = (int*)(xregion + (size_t)BB * NN * sizeof(double));
    float* out_tokens = (float*)d_out;                       // [B,K,D] fp32
    float* out_idx = out_tokens + (size_t)BB * KK * DD;      // [B,K] indices as fp32

    norm_kernel<<<BB * NN, 256, 0, stream>>>(hs, inv);
    sim_kernel<<<dim3(45, 1, BB), 256, 0, stream>>>(hs, inv, sim);
    init_gain_kernel<<<dim3(NN / 4, BB), 256, 0, stream>>>(sim, g0);
    select_kernel<<<BB, 576, 0, stream>>>(sim, g0, cls, out_idx, gsorted);
    gather_kernel<<<BB * KK, 256, 0, stream>>>(hs, gsorted, out_tokens);
}